// Round 1
// baseline (1478.696 us; speedup 1.0000x reference)
//
#include <hip/hip_runtime.h>
#include <math.h>

#define NT 256
#define BR 16

// Fully fused f64 MLP decoder.
// Rationale: binary mask outputs make this a threshold-flip problem; fp32
// GEMMs flip ~3 masks vs an fp64 reference. Full f64 compute matches the
// reference to ~1e-15 in the logits -> flip probability ~0.
__global__ __launch_bounds__(NT, 2)
void dec_fused(const float* __restrict__ z,
               const float* __restrict__ W1, const float* __restrict__ b1,
               const float* __restrict__ W2, const float* __restrict__ b2,
               const float* __restrict__ W3, const float* __restrict__ b3,
               const float* __restrict__ W4, const float* __restrict__ b4,
               const float* __restrict__ adj,
               float* __restrict__ out, int B)
{
    // One 64 KB buffer, reused: z^T -> h1^T -> h2^T -> h3^T, layout [k][r]
    // (r fastest). Wave lanes share r-group -> LDS reads are broadcasts.
    __shared__ double hT[512 * BR];
    __shared__ double logitsS[BR * 20];
    __shared__ float  maskS[BR * 20];
    __shared__ float  adjS[400];

    const int tid = threadIdx.x;
    const int rg  = tid >> 6;       // wave id 0..3 -> row group
    const int cg  = tid & 63;       // lane -> column group
    const int r0  = rg * 4;         // 4 rows per thread
    const int rowBase = blockIdx.x * BR;

    const int O_MASK  = B * 400;
    const int O_PROBS = O_MASK + B * 20;
    const int O_LOSS  = O_PROBS + B * 20;

    for (int i = tid; i < 400; i += NT) adjS[i] = adj[i];

    // ---- stage z^T as f64 (cast is exact) ----
    for (int i = tid; i < 512 * BR; i += NT) {
        int k = i & 511, r = i >> 9;
        hT[k * BR + r] = (double)z[(rowBase + r) * 512 + k];
    }
    __syncthreads();

    // ---------------- layer 1: 512 -> 512, relu ----------------
    {
        const float4* W1v = (const float4*)W1;
        double a1[4][8];
#pragma unroll
        for (int ri = 0; ri < 4; ++ri)
#pragma unroll
            for (int ci = 0; ci < 8; ++ci) a1[ri][ci] = 0.0;

        for (int k = 0; k < 512; ++k) {
            double zr[4];
#pragma unroll
            for (int ri = 0; ri < 4; ++ri) zr[ri] = hT[k * BR + r0 + ri];
            float4 w0 = W1v[k * 128 + cg * 2 + 0];
            float4 w1 = W1v[k * 128 + cg * 2 + 1];
            double wd[8] = {(double)w0.x, (double)w0.y, (double)w0.z, (double)w0.w,
                            (double)w1.x, (double)w1.y, (double)w1.z, (double)w1.w};
#pragma unroll
            for (int ci = 0; ci < 8; ++ci)
#pragma unroll
                for (int ri = 0; ri < 4; ++ri)
                    a1[ri][ci] += zr[ri] * wd[ci];
        }
        __syncthreads();   // done reading z^T
#pragma unroll
        for (int ci = 0; ci < 8; ++ci) {
            int c = cg * 8 + ci;
            double bb = (double)b1[c];
#pragma unroll
            for (int ri = 0; ri < 4; ++ri) {
                double v = a1[ri][ci] + bb;
                hT[c * BR + r0 + ri] = v > 0.0 ? v : 0.0;
            }
        }
        __syncthreads();
    }

    // ---------------- layer 2: 512 -> 256, relu ----------------
    {
        const float4* W2v = (const float4*)W2;
        double a2[4][4];
#pragma unroll
        for (int ri = 0; ri < 4; ++ri)
#pragma unroll
            for (int ci = 0; ci < 4; ++ci) a2[ri][ci] = 0.0;

        for (int k = 0; k < 512; ++k) {
            double zr[4];
#pragma unroll
            for (int ri = 0; ri < 4; ++ri) zr[ri] = hT[k * BR + r0 + ri];
            float4 w = W2v[k * 64 + cg];
            double wd[4] = {(double)w.x, (double)w.y, (double)w.z, (double)w.w};
#pragma unroll
            for (int ci = 0; ci < 4; ++ci)
#pragma unroll
                for (int ri = 0; ri < 4; ++ri)
                    a2[ri][ci] += zr[ri] * wd[ci];
        }
        __syncthreads();   // done reading h1^T
#pragma unroll
        for (int ci = 0; ci < 4; ++ci) {
            int c = cg * 4 + ci;
            double bb = (double)b2[c];
#pragma unroll
            for (int ri = 0; ri < 4; ++ri) {
                double v = a2[ri][ci] + bb;
                hT[c * BR + r0 + ri] = v > 0.0 ? v : 0.0;
            }
        }
        __syncthreads();
    }

    // ---------------- layer 3: 256 -> 128, relu ----------------
    {
        const float2* W3v = (const float2*)W3;
        double a3[4][2];
#pragma unroll
        for (int ri = 0; ri < 4; ++ri)
#pragma unroll
            for (int ci = 0; ci < 2; ++ci) a3[ri][ci] = 0.0;

        for (int k = 0; k < 256; ++k) {
            double zr[4];
#pragma unroll
            for (int ri = 0; ri < 4; ++ri) zr[ri] = hT[k * BR + r0 + ri];
            float2 w = W3v[k * 64 + cg];
            double wd[2] = {(double)w.x, (double)w.y};
#pragma unroll
            for (int ci = 0; ci < 2; ++ci)
#pragma unroll
                for (int ri = 0; ri < 4; ++ri)
                    a3[ri][ci] += zr[ri] * wd[ci];
        }
        __syncthreads();   // done reading h2^T
#pragma unroll
        for (int ci = 0; ci < 2; ++ci) {
            int c = cg * 2 + ci;
            double bb = (double)b3[c];
#pragma unroll
            for (int ri = 0; ri < 4; ++ri) {
                double v = a3[ri][ci] + bb;
                hT[c * BR + r0 + ri] = v > 0.0 ? v : 0.0;
            }
        }
        __syncthreads();
    }

    // ---------------- layer 4: 128 -> 20, logits ----------------
    for (int o = tid; o < BR * 20; o += NT) {
        int r = o / 20, c = o - r * 20;
        double acc = (double)b4[c];
        for (int k = 0; k < 128; ++k)
            acc += hT[k * BR + r] * (double)W4[k * 20 + c];
        logitsS[o] = acc;
    }
    __syncthreads();

    // ---------------- epilogue: probs, mask, adj, loss ----------------
    for (int o = tid; o < BR * 20; o += NT) {
        double lg = logitsS[o];
        double p  = 1.0 / (1.0 + exp(-lg));
        out[O_PROBS + rowBase * 20 + o] = (float)p;
        float m = lg > 0.0 ? 1.0f : 0.0f;   // == (sigmoid(lg) > 0.5) in f64
        out[O_MASK + rowBase * 20 + o] = m;
        maskS[o] = m;
    }
    __syncthreads();

    for (int i = tid; i < BR * 400; i += NT) {
        int r  = i / 400;
        int e  = i - r * 400;
        int ii = e / 20;
        int jj = e - ii * 20;
        out[(rowBase + r) * 400 + e] = maskS[r * 20 + ii] * maskS[r * 20 + jj] * adjS[e];
    }

    if (blockIdx.x == 0 && tid == 0) out[O_LOSS] = 0.0f;
}

extern "C" void kernel_launch(void* const* d_in, const int* in_sizes, int n_in,
                              void* d_out, int out_size, void* d_ws, size_t ws_size,
                              hipStream_t stream) {
    const float* z   = (const float*)d_in[0];
    const float* W1  = (const float*)d_in[1];
    const float* b1  = (const float*)d_in[2];
    const float* W2  = (const float*)d_in[3];
    const float* b2  = (const float*)d_in[4];
    const float* W3  = (const float*)d_in[5];
    const float* b3  = (const float*)d_in[6];
    const float* W4  = (const float*)d_in[7];
    const float* b4  = (const float*)d_in[8];
    const float* adj = (const float*)d_in[9];
    float* out = (float*)d_out;

    const int B = in_sizes[0] / 512;   // 65536
    const int nBlocks = B / BR;        // 4096

    hipLaunchKernelGGL(dec_fused, dim3(nBlocks), dim3(NT), 0, stream,
                       z, W1, b1, W2, b2, W3, b3, W4, b4, adj, out, B);
}